// Round 21
// baseline (183.989 us; speedup 1.0000x reference)
//
#include <hip/hip_runtime.h>
#include <math.h>

#define N_NODES   500000
#define N_EDGES   16000000
#define EPS       1e-6f

#define NBINS         256      // bin = dst >> 11  (2048 nodes per bin)
#define NODES_PER_BIN 2048
#define CHUNK         8192     // edges per hist/scatter block
#define NBLK_A        1954     // ceil(16e6 / 8192)
#define SPLIT         8        // reduce splits per bin

typedef unsigned long long u64;
typedef unsigned int u32;
typedef unsigned short u16;
typedef u32 v4u __attribute__((ext_vector_type(4)));

// u32 record: [0:11) lid = dst & 2047, [11:30) srcid, [30:32) spare.
// recbuf is GLOBALLY bin-contiguous; S[k] padded to x4 records (+16 u32 slack
// at the end so an unconditional 8-wide tail read stays in-bounds).

// ---- Phase A1: per-(block,bin) histogram (dst only) ----
__global__ void __launch_bounds__(512) hist_kernel(
    const int* __restrict__ dst, u32* __restrict__ counts)
{
    __shared__ u32 hist[NBINS];
    int t = threadIdx.x, b = blockIdx.x;
    if (t < NBINS) hist[t] = 0;
    __syncthreads();
    const v4u* dst4 = reinterpret_cast<const v4u*>(dst);
    int base4 = b * (CHUNK / 4);
    #pragma unroll
    for (int i = 0; i < 4; ++i) {
        int e4 = base4 + t + i * 512;
        if (e4 * 4 < N_EDGES) {
            v4u d4 = __builtin_nontemporal_load(dst4 + e4);
            #pragma unroll
            for (int j = 0; j < 4; ++j) {
                u32 d_ = (u32)min(max((int)d4[j], 0), N_NODES - 1);
                atomicAdd(&hist[d_ >> 11], 1u);
            }
        }
    }
    __syncthreads();
    if (t < NBINS) counts[(size_t)b * NBINS + t] = hist[t];
}

// ---- Phase A2a: per-bin exclusive prefix over blocks (in place) + totals ----
__global__ void __launch_bounds__(256) scanblk_kernel(
    u32* __restrict__ counts, u32* __restrict__ T)
{
    __shared__ u32 sb[256];
    int t = threadIdx.x, k = blockIdx.x;
    u32 c[8], l[8];
    u32 s = 0;
    #pragma unroll
    for (int i = 0; i < 8; ++i) {
        int b = t * 8 + i;
        c[i] = (b < NBLK_A) ? counts[(size_t)b * NBINS + k] : 0;
        l[i] = s;
        s += c[i];
    }
    sb[t] = s;
    __syncthreads();
    for (int off = 1; off < 256; off <<= 1) {
        u32 v = sb[t];
        u32 a = (t >= off) ? sb[t - off] : 0;
        __syncthreads();
        sb[t] = v + a;
        __syncthreads();
    }
    u32 excl = sb[t] - s;
    #pragma unroll
    for (int i = 0; i < 8; ++i) {
        int b = t * 8 + i;
        if (b < NBLK_A) counts[(size_t)b * NBINS + k] = excl + l[i];
    }
    if (t == 255) T[k] = sb[255];
}

// ---- Phase A2b: padded exclusive scan of bin totals -> S, keep lengths ----
__global__ void __launch_bounds__(NBINS) scanbin_kernel(
    const u32* __restrict__ T, u32* __restrict__ S, u32* __restrict__ Tlen)
{
    __shared__ u32 sb[NBINS];
    int t = threadIdx.x;
    u32 own = T[t];
    u32 p4 = (own + 3u) & ~3u;          // pad each bin to x4 records
    sb[t] = p4;
    __syncthreads();
    for (int off = 1; off < NBINS; off <<= 1) {
        u32 v = sb[t];
        u32 a = (t >= off) ? sb[t - off] : 0;
        __syncthreads();
        sb[t] = v + a;
        __syncthreads();
    }
    if (t == 0) S[0] = 0;
    S[t + 1] = sb[t];
    Tlen[t] = own;
}

// ---- Phase A3: integer counting sort with GLOBAL bin-contiguous writeout ----
__global__ void __launch_bounds__(512) scatter_kernel(
    const int* __restrict__ src, const int* __restrict__ dst,
    const u32* __restrict__ P, const u32* __restrict__ S,
    u32* __restrict__ recbuf)
{
    __shared__ u32 stage[CHUNK];       // 32 KB — records at arrival slot
    __shared__ u16 perm[CHUNK];        // 16 KB — sorted pos -> slot
    __shared__ u32 incl[NBINS];        // 1 KB
    __shared__ u32 gbase[NBINS];       // 1 KB
    __shared__ u32 wsum[4];

    int t = threadIdx.x, b = blockIdx.x;
    int lane = t & 63, wid = t >> 6;
    if (t < NBINS) {
        gbase[t] = S[t] + P[(size_t)b * NBINS + t];
        incl[t] = 0;
    }
    __syncthreads();

    const v4u* src4 = reinterpret_cast<const v4u*>(src);
    const v4u* dst4 = reinterpret_cast<const v4u*>(dst);
    int base4 = b * (CHUNK / 4);

    u32 rb[16];                        // bin(8) << 13 | rank(13); ~0u = invalid
    #pragma unroll
    for (int i = 0; i < 4; ++i) {
        int e4 = base4 + t + i * 512;
        #pragma unroll
        for (int j = 0; j < 4; ++j) rb[i * 4 + j] = 0xFFFFFFFFu;
        if (e4 * 4 < N_EDGES) {
            v4u s4 = __builtin_nontemporal_load(src4 + e4);
            v4u d4 = __builtin_nontemporal_load(dst4 + e4);
            #pragma unroll
            for (int j = 0; j < 4; ++j) {
                u32 s_ = (u32)min(max((int)s4[j], 0), N_NODES - 1);
                u32 d_ = (u32)min(max((int)d4[j], 0), N_NODES - 1);
                u32 rc = (s_ << 11) | (d_ & (NODES_PER_BIN - 1));
                int kk = i * 4 + j;
                stage[t + kk * 512] = rc;
                u32 bin = d_ >> 11;
                u32 r = atomicAdd(&incl[bin], 1u);
                rb[kk] = (bin << 13) | r;
            }
        }
    }
    __syncthreads();

    // inclusive scan of incl[256] (4 waves)
    u32 v = 0;
    if (t < NBINS) {
        v = incl[t];
        #pragma unroll
        for (int off = 1; off < 64; off <<= 1) {
            u32 u_ = __shfl_up(v, off, 64);
            if (lane >= off) v += u_;
        }
        if (lane == 63) wsum[wid] = v;
    }
    __syncthreads();
    if (t < NBINS) {
        u32 pre = 0;
        #pragma unroll
        for (int w2 = 0; w2 < 4; ++w2)
            pre += (w2 < wid) ? wsum[w2] : 0;
        v += pre;
        incl[t] = v;
    }
    __syncthreads();

    #pragma unroll
    for (int kk = 0; kk < 16; ++kk) {
        if (rb[kk] != 0xFFFFFFFFu) {
            u32 bin = rb[kk] >> 13;
            u32 r   = rb[kk] & 8191u;
            u32 excl = bin ? incl[bin - 1] : 0;
            perm[excl + r] = (u16)(t + kk * 512);
        }
    }
    __syncthreads();

    // writeout to global bin-contiguous regions
    u32 total = incl[NBINS - 1];
    for (u32 j = t; j < total; j += 512) {
        u32 rc = stage[perm[j]];
        u32 lo = 0, hi = NBINS - 1;
        #pragma unroll
        for (int it = 0; it < 8; ++it) {
            u32 mid = (lo + hi) >> 1;
            if (j < incl[mid]) hi = mid; else lo = mid + 1;
        }
        u32 excl = lo ? incl[lo - 1] : 0;
        recbuf[gbase[lo] + (j - excl)] = rc;
    }
}

// ---- Phase B: flat split-K decode + accumulate; LDS pos window + asm MLP-8 ----
__global__ void __launch_bounds__(512) reduce_kernel(
    const u32* __restrict__ recbuf, const u32* __restrict__ S,
    const u32* __restrict__ Tlen, const float* __restrict__ pos,
    u64* __restrict__ partial)
{
    __shared__ u64 acc[NODES_PER_BIN];     // 16 KB
    __shared__ float2 pwin[NODES_PER_BIN]; // 16 KB — bin's pos window (dst side)
    int t = threadIdx.x;
    int k = blockIdx.x / SPLIT;
    int s = blockIdx.x % SPLIT;
    int nodebase = k * NODES_PER_BIN;
    const float2* pos2 = reinterpret_cast<const float2*>(pos);
    #pragma unroll
    for (int i = 0; i < 4; ++i) {
        int idx = t + i * 512;
        acc[idx] = 0;
        pwin[idx] = pos2[min(nodebase + idx, N_NODES - 1)];
    }
    __syncthreads();

    u32 base = S[k];                     // 4-record aligned
    u32 len  = Tlen[k];
    u32 lo = (u32)(((u64)len * s / SPLIT) & ~3ull);
    u32 hi = (s == SPLIT - 1) ? len : (u32)(((u64)len * (s + 1) / SPLIT) & ~3ull);

    const u32* seg = recbuf + base;

    for (u32 j = lo + (u32)t * 8; j < hi; j += 4096) {
        v4u a4 = *reinterpret_cast<const v4u*>(seg + j);       // aligned 16B
        v4u b4 = *reinterpret_cast<const v4u*>(seg + j + 4);   // slack-covered
        u32 n = hi - j;                                         // 1..8 valid
        u32 rc0 = a4[0], rc1 = a4[1], rc2 = a4[2], rc3 = a4[3];
        u32 rc4 = b4[0], rc5 = b4[1], rc6 = b4[2], rc7 = b4[3];
        u32 lid0 = rc0 & (NODES_PER_BIN - 1), sx0 = min(rc0 >> 11, (u32)(N_NODES - 1));
        u32 lid1 = rc1 & (NODES_PER_BIN - 1), sx1 = min(rc1 >> 11, (u32)(N_NODES - 1));
        u32 lid2 = rc2 & (NODES_PER_BIN - 1), sx2 = min(rc2 >> 11, (u32)(N_NODES - 1));
        u32 lid3 = rc3 & (NODES_PER_BIN - 1), sx3 = min(rc3 >> 11, (u32)(N_NODES - 1));
        u32 lid4 = rc4 & (NODES_PER_BIN - 1), sx4 = min(rc4 >> 11, (u32)(N_NODES - 1));
        u32 lid5 = rc5 & (NODES_PER_BIN - 1), sx5 = min(rc5 >> 11, (u32)(N_NODES - 1));
        u32 lid6 = rc6 & (NODES_PER_BIN - 1), sx6 = min(rc6 >> 11, (u32)(N_NODES - 1));
        u32 lid7 = rc7 & (NODES_PER_BIN - 1), sx7 = min(rc7 >> 11, (u32)(N_NODES - 1));

        // 8 independent src-pos gathers in flight; single waitcnt.
        float2 ps0, ps1, ps2, ps3, ps4, ps5, ps6, ps7;
        asm volatile(
            "global_load_dwordx2 %0, %8, off\n\t"
            "global_load_dwordx2 %1, %9, off\n\t"
            "global_load_dwordx2 %2, %10, off\n\t"
            "global_load_dwordx2 %3, %11, off\n\t"
            "global_load_dwordx2 %4, %12, off\n\t"
            "global_load_dwordx2 %5, %13, off\n\t"
            "global_load_dwordx2 %6, %14, off\n\t"
            "global_load_dwordx2 %7, %15, off\n\t"
            "s_waitcnt vmcnt(0)"
            : "=&v"(ps0), "=&v"(ps1), "=&v"(ps2), "=&v"(ps3),
              "=&v"(ps4), "=&v"(ps5), "=&v"(ps6), "=&v"(ps7)
            : "v"(pos2 + sx0), "v"(pos2 + sx1), "v"(pos2 + sx2), "v"(pos2 + sx3),
              "v"(pos2 + sx4), "v"(pos2 + sx5), "v"(pos2 + sx6), "v"(pos2 + sx7));

        // dst-pos from the LDS window (no TA traffic)
        float2 pd0 = pwin[lid0];
        float2 pd1 = pwin[lid1];
        float2 pd2 = pwin[lid2];
        float2 pd3 = pwin[lid3];
        float2 pd4 = pwin[lid4];
        float2 pd5 = pwin[lid5];
        float2 pd6 = pwin[lid6];
        float2 pd7 = pwin[lid7];

#define BODY(PS, PD, LID, COND)                                               \
        if (COND) {                                                           \
            float dx = PS.x - PD.x, dy = PS.y - PD.y;                         \
            float nrm = sqrtf(dx * dx + dy * dy) + EPS;                       \
            float inv = 1.0f / nrm;                                           \
            float ux = dx * inv, uy = dy * inv;                               \
            float cdx = fminf(fmaxf(dx, -12.0f), 12.0f);                      \
            float cdy = fminf(fmaxf(dy, -12.0f), 12.0f);                      \
            u64 w = (u64)(u32)__float2int_rn((cdx + 12.0f) * 16.0f)           \
                  | ((u64)(u32)__float2int_rn((cdy + 12.0f) * 16.0f) << 16)   \
                  | ((u64)(u32)__float2int_rn((ux + 1.0f) * 16.0f) << 32)     \
                  | ((u64)(u32)__float2int_rn((uy + 1.0f) * 16.0f) << 44)     \
                  | (1ULL << 56);                                             \
            atomicAdd(&acc[LID], w);                                          \
        }

        BODY(ps0, pd0, lid0, true)
        BODY(ps1, pd1, lid1, n > 1)
        BODY(ps2, pd2, lid2, n > 2)
        BODY(ps3, pd3, lid3, n > 3)
        BODY(ps4, pd4, lid4, n > 4)
        BODY(ps5, pd5, lid5, n > 5)
        BODY(ps6, pd6, lid6, n > 6)
        BODY(ps7, pd7, lid7, n > 7)
#undef BODY
    }
    __syncthreads();

    u64* dstp = partial + ((size_t)k * SPLIT + s) * NODES_PER_BIN;
    #pragma unroll
    for (int i = 0; i < 4; ++i) {
        int idx = t + i * 512;
        __builtin_nontemporal_store(acc[idx], dstp + idx);
    }
}

// ---- Phase C: combine partials + finalize ----
__global__ void __launch_bounds__(512) combine_kernel(
    const u64* __restrict__ partial, const float* __restrict__ pos,
    float* __restrict__ out)
{
    int i = blockIdx.x * 512 + threadIdx.x;
    if (i >= N_NODES) return;
    int k = i >> 11;
    int lid = i & (NODES_PER_BIN - 1);
    const u64* p = partial + (size_t)k * SPLIT * NODES_PER_BIN + lid;
    u64 w = 0;
    #pragma unroll
    for (int s = 0; s < SPLIT; ++s)
        w += __builtin_nontemporal_load(p + (size_t)s * NODES_PER_BIN);

    float cnt = (float)(u32)(w >> 56);
    float sdx = (float)(u32)(w & 0xFFFFULL)         * (1.0f/16.0f) - 12.0f * cnt;
    float sdy = (float)(u32)((w >> 16) & 0xFFFFULL) * (1.0f/16.0f) - 12.0f * cnt;
    float sux = (float)(u32)((w >> 32) & 0xFFFULL)  * (1.0f/16.0f) -  1.0f * cnt;
    float suy = (float)(u32)((w >> 44) & 0xFFFULL)  * (1.0f/16.0f) -  1.0f * cnt;
    float invc = 1.0f / fmaxf(cnt, 1.0f);
    float2 pp = reinterpret_cast<const float2*>(pos)[i];
    float* row = out + (size_t)i * 6;
    row[0] = sdx * invc;
    row[1] = sdy * invc;
    row[2] = sux * invc;
    row[3] = suy * invc;
    row[4] = pp.x;
    row[5] = pp.y;
}

// ---------------- Fallback (round-3 single-atomic path) ----------------
__global__ void __launch_bounds__(256) edge_scatter_kernel(
    const int* __restrict__ src, const int* __restrict__ dst,
    const float* __restrict__ pos, u64* __restrict__ acc)
{
    int e = blockIdx.x * blockDim.x + threadIdx.x;
    if (e >= N_EDGES) return;
    int s = src[e];
    int d = dst[e];
    if ((unsigned)s >= (unsigned)N_NODES || (unsigned)d >= (unsigned)N_NODES) return;
    float2 ps = reinterpret_cast<const float2*>(pos)[s];
    float2 pd = reinterpret_cast<const float2*>(pos)[d];
    float dx = ps.x - pd.x, dy = ps.y - pd.y;
    float nrm = sqrtf(dx*dx + dy*dy) + EPS;
    float inv = 1.0f / nrm;
    float ux = dx * inv, uy = dy * inv;
    float cdx = fminf(fmaxf(dx, -12.0f), 12.0f);
    float cdy = fminf(fmaxf(dy, -12.0f), 12.0f);
    u64 qdx = (u64)(u32)__float2int_rn((cdx + 12.0f) * 16.0f);
    u64 qdy = (u64)(u32)__float2int_rn((cdy + 12.0f) * 16.0f);
    u64 qux = (u64)(u32)__float2int_rn((ux + 1.0f) * 16.0f);
    u64 quy = (u64)(u32)__float2int_rn((uy + 1.0f) * 16.0f);
    u64 w = qdx | (qdy << 16) | (qux << 32) | (quy << 44) | (1ULL << 56);
    atomicAdd(acc + (size_t)d * 3, w);
}

__global__ void __launch_bounds__(256) node_finalize_kernel(
    const float* __restrict__ pos, float* __restrict__ out)
{
    int i = blockIdx.x * blockDim.x + threadIdx.x;
    if (i >= N_NODES) return;
    u64 w = reinterpret_cast<const u64*>(out)[(size_t)i * 3];
    float cnt = (float)(u32)(w >> 56);
    float sdx = (float)(u32)(w & 0xFFFFULL)         * (1.0f/16.0f) - 12.0f * cnt;
    float sdy = (float)(u32)((w >> 16) & 0xFFFFULL) * (1.0f/16.0f) - 12.0f * cnt;
    float sux = (float)(u32)((w >> 32) & 0xFFFULL)  * (1.0f/16.0f) -  1.0f * cnt;
    float suy = (float)(u32)((w >> 44) & 0xFFFULL)  * (1.0f/16.0f) -  1.0f * cnt;
    float invc = 1.0f / fmaxf(cnt, 1.0f);
    float2 p = reinterpret_cast<const float2*>(pos)[i];
    float* row = out + (size_t)i * 6;
    row[0] = sdx * invc; row[1] = sdy * invc;
    row[2] = sux * invc; row[3] = suy * invc;
    row[4] = p.x; row[5] = p.y;
}

extern "C" void kernel_launch(void* const* d_in, const int* in_sizes, int n_in,
                              void* d_out, int out_size, void* d_ws, size_t ws_size,
                              hipStream_t stream)
{
    const float* pos = (const float*)d_in[0];
    const int* edge_index = (const int*)d_in[1];
    const int* src = edge_index;
    const int* dst = edge_index + N_EDGES;
    float* out = (float*)d_out;

    size_t need_rec    = ((size_t)N_EDGES + 4 * NBINS + 16) * sizeof(u32);      // ~64 MB
    size_t need_counts = (size_t)NBLK_A * NBINS * sizeof(u32);                  // ~2 MB
    size_t need_T      = (size_t)NBINS * sizeof(u32);
    size_t need_S      = (size_t)(NBINS + 1) * sizeof(u32);
    size_t need_Tlen   = (size_t)NBINS * sizeof(u32);
    size_t need_part   = (size_t)NBINS * SPLIT * NODES_PER_BIN * sizeof(u64);   // 32 MB
    size_t need = need_rec + need_counts + need_T + need_S + need_Tlen + need_part + 512;

    if (ws_size < need) {
        // Fallback: single-u64-atomic path (round 3)
        (void)hipMemsetAsync(d_out, 0, (size_t)out_size * sizeof(float), stream);
        int eblocks = (N_EDGES + 255) / 256;
        edge_scatter_kernel<<<eblocks, 256, 0, stream>>>(
            src, dst, pos, reinterpret_cast<u64*>(out));
        int nblocks = (N_NODES + 255) / 256;
        node_finalize_kernel<<<nblocks, 256, 0, stream>>>(pos, out);
        return;
    }

    char* w = (char*)d_ws;
    u32* recbuf  = (u32*)w;           w += need_rec;
    u32* counts  = (u32*)w;           w += need_counts;
    u32* T       = (u32*)w;           w += need_T;
    u32* S       = (u32*)w;           w += need_S;
    u32* Tlen    = (u32*)w;           w += need_Tlen;
    u64* partial = (u64*)w;

    hist_kernel   <<<NBLK_A, 512, 0, stream>>>(dst, counts);
    scanblk_kernel<<<NBINS,  256, 0, stream>>>(counts, T);
    scanbin_kernel<<<1,    NBINS, 0, stream>>>(T, S, Tlen);
    scatter_kernel<<<NBLK_A, 512, 0, stream>>>(src, dst, counts, S, recbuf);
    reduce_kernel <<<NBINS * SPLIT, 512, 0, stream>>>(recbuf, S, Tlen, pos, partial);
    combine_kernel<<<(N_NODES + 511) / 512, 512, 0, stream>>>(partial, pos, out);
}

// Round 22
// 180.485 us; speedup vs baseline: 1.0194x; 1.0194x over previous
//
#include <hip/hip_runtime.h>
#include <math.h>

#define N_NODES   500000
#define N_EDGES   16000000
#define EPS       1e-6f

#define NBINS         256      // bin = dst >> 11  (2048 nodes per bin)
#define NODES_PER_BIN 2048
#define CHUNK         8192     // edges per hist/scatter block
#define NBLK_A        1954     // ceil(16e6 / 8192)
#define SPLIT         8        // reduce splits per bin

typedef unsigned long long u64;
typedef unsigned int u32;
typedef unsigned short u16;
typedef u32 v4u __attribute__((ext_vector_type(4)));

// u32 record: [0:11) lid = dst & 2047, [11:30) srcid, [30:32) spare.
// recbuf is GLOBALLY bin-contiguous; S[k] padded to x4 records.

// ---- Phase A1: per-(block,bin) histogram (dst only) ----
__global__ void __launch_bounds__(512) hist_kernel(
    const int* __restrict__ dst, u32* __restrict__ counts)
{
    __shared__ u32 hist[NBINS];
    int t = threadIdx.x, b = blockIdx.x;
    if (t < NBINS) hist[t] = 0;
    __syncthreads();
    const v4u* dst4 = reinterpret_cast<const v4u*>(dst);
    int base4 = b * (CHUNK / 4);
    #pragma unroll
    for (int i = 0; i < 4; ++i) {
        int e4 = base4 + t + i * 512;
        if (e4 * 4 < N_EDGES) {
            v4u d4 = __builtin_nontemporal_load(dst4 + e4);
            #pragma unroll
            for (int j = 0; j < 4; ++j) {
                u32 d_ = (u32)min(max((int)d4[j], 0), N_NODES - 1);
                atomicAdd(&hist[d_ >> 11], 1u);
            }
        }
    }
    __syncthreads();
    if (t < NBINS) counts[(size_t)b * NBINS + t] = hist[t];
}

// ---- Phase A2a: per-bin exclusive prefix over blocks (in place) + totals ----
__global__ void __launch_bounds__(256) scanblk_kernel(
    u32* __restrict__ counts, u32* __restrict__ T)
{
    __shared__ u32 sb[256];
    int t = threadIdx.x, k = blockIdx.x;
    u32 c[8], l[8];
    u32 s = 0;
    #pragma unroll
    for (int i = 0; i < 8; ++i) {
        int b = t * 8 + i;
        c[i] = (b < NBLK_A) ? counts[(size_t)b * NBINS + k] : 0;
        l[i] = s;
        s += c[i];
    }
    sb[t] = s;
    __syncthreads();
    for (int off = 1; off < 256; off <<= 1) {
        u32 v = sb[t];
        u32 a = (t >= off) ? sb[t - off] : 0;
        __syncthreads();
        sb[t] = v + a;
        __syncthreads();
    }
    u32 excl = sb[t] - s;
    #pragma unroll
    for (int i = 0; i < 8; ++i) {
        int b = t * 8 + i;
        if (b < NBLK_A) counts[(size_t)b * NBINS + k] = excl + l[i];
    }
    if (t == 255) T[k] = sb[255];
}

// ---- Phase A2b: padded exclusive scan of bin totals -> S, keep lengths ----
__global__ void __launch_bounds__(NBINS) scanbin_kernel(
    const u32* __restrict__ T, u32* __restrict__ S, u32* __restrict__ Tlen)
{
    __shared__ u32 sb[NBINS];
    int t = threadIdx.x;
    u32 own = T[t];
    u32 p4 = (own + 3u) & ~3u;          // pad each bin to x4 records
    sb[t] = p4;
    __syncthreads();
    for (int off = 1; off < NBINS; off <<= 1) {
        u32 v = sb[t];
        u32 a = (t >= off) ? sb[t - off] : 0;
        __syncthreads();
        sb[t] = v + a;
        __syncthreads();
    }
    if (t == 0) S[0] = 0;
    S[t + 1] = sb[t];
    Tlen[t] = own;
}

// ---- Phase A3: integer counting sort with GLOBAL bin-contiguous writeout ----
__global__ void __launch_bounds__(512) scatter_kernel(
    const int* __restrict__ src, const int* __restrict__ dst,
    const u32* __restrict__ P, const u32* __restrict__ S,
    u32* __restrict__ recbuf)
{
    __shared__ u32 stage[CHUNK];       // 32 KB — records at arrival slot
    __shared__ u16 perm[CHUNK];        // 16 KB — sorted pos -> slot
    __shared__ u32 incl[NBINS];        // 1 KB
    __shared__ u32 gbase[NBINS];       // 1 KB
    __shared__ u32 wsum[4];

    int t = threadIdx.x, b = blockIdx.x;
    int lane = t & 63, wid = t >> 6;
    if (t < NBINS) {
        gbase[t] = S[t] + P[(size_t)b * NBINS + t];
        incl[t] = 0;
    }
    __syncthreads();

    const v4u* src4 = reinterpret_cast<const v4u*>(src);
    const v4u* dst4 = reinterpret_cast<const v4u*>(dst);
    int base4 = b * (CHUNK / 4);

    u32 rb[16];                        // bin(8) << 13 | rank(13); ~0u = invalid
    #pragma unroll
    for (int i = 0; i < 4; ++i) {
        int e4 = base4 + t + i * 512;
        #pragma unroll
        for (int j = 0; j < 4; ++j) rb[i * 4 + j] = 0xFFFFFFFFu;
        if (e4 * 4 < N_EDGES) {
            v4u s4 = __builtin_nontemporal_load(src4 + e4);
            v4u d4 = __builtin_nontemporal_load(dst4 + e4);
            #pragma unroll
            for (int j = 0; j < 4; ++j) {
                u32 s_ = (u32)min(max((int)s4[j], 0), N_NODES - 1);
                u32 d_ = (u32)min(max((int)d4[j], 0), N_NODES - 1);
                u32 rc = (s_ << 11) | (d_ & (NODES_PER_BIN - 1));
                int kk = i * 4 + j;
                stage[t + kk * 512] = rc;
                u32 bin = d_ >> 11;
                u32 r = atomicAdd(&incl[bin], 1u);
                rb[kk] = (bin << 13) | r;
            }
        }
    }
    __syncthreads();

    // inclusive scan of incl[256] (4 waves)
    u32 v = 0;
    if (t < NBINS) {
        v = incl[t];
        #pragma unroll
        for (int off = 1; off < 64; off <<= 1) {
            u32 u_ = __shfl_up(v, off, 64);
            if (lane >= off) v += u_;
        }
        if (lane == 63) wsum[wid] = v;
    }
    __syncthreads();
    if (t < NBINS) {
        u32 pre = 0;
        #pragma unroll
        for (int w2 = 0; w2 < 4; ++w2)
            pre += (w2 < wid) ? wsum[w2] : 0;
        v += pre;
        incl[t] = v;
    }
    __syncthreads();

    #pragma unroll
    for (int kk = 0; kk < 16; ++kk) {
        if (rb[kk] != 0xFFFFFFFFu) {
            u32 bin = rb[kk] >> 13;
            u32 r   = rb[kk] & 8191u;
            u32 excl = bin ? incl[bin - 1] : 0;
            perm[excl + r] = (u16)(t + kk * 512);
        }
    }
    __syncthreads();

    // writeout to global bin-contiguous regions
    u32 total = incl[NBINS - 1];
    for (u32 j = t; j < total; j += 512) {
        u32 rc = stage[perm[j]];
        u32 lo = 0, hi = NBINS - 1;
        #pragma unroll
        for (int it = 0; it < 8; ++it) {
            u32 mid = (lo + hi) >> 1;
            if (j < incl[mid]) hi = mid; else lo = mid + 1;
        }
        u32 excl = lo ? incl[lo - 1] : 0;
        recbuf[gbase[lo] + (j - excl)] = rc;
    }
}

// ---- Phase B: flat split-K decode + accumulate; LDS pos window + asm MLP-4 ----
__global__ void __launch_bounds__(512) reduce_kernel(
    const u32* __restrict__ recbuf, const u32* __restrict__ S,
    const u32* __restrict__ Tlen, const float* __restrict__ pos,
    u64* __restrict__ partial)
{
    __shared__ u64 acc[NODES_PER_BIN];     // 16 KB
    __shared__ float2 pwin[NODES_PER_BIN]; // 16 KB — bin's pos window (dst side)
    int t = threadIdx.x;
    int k = blockIdx.x / SPLIT;
    int s = blockIdx.x % SPLIT;
    int nodebase = k * NODES_PER_BIN;
    const float2* pos2 = reinterpret_cast<const float2*>(pos);
    #pragma unroll
    for (int i = 0; i < 4; ++i) {
        int idx = t + i * 512;
        acc[idx] = 0;
        pwin[idx] = pos2[min(nodebase + idx, N_NODES - 1)];
    }
    __syncthreads();

    u32 base = S[k];                     // 4-record aligned
    u32 len  = Tlen[k];
    u32 lo = (u32)(((u64)len * s / SPLIT) & ~3ull);
    u32 hi = (s == SPLIT - 1) ? len : (u32)(((u64)len * (s + 1) / SPLIT) & ~3ull);

    const u32* seg = recbuf + base;

    for (u32 j = lo + (u32)t * 4; j < hi; j += 2048) {
        v4u r4 = *reinterpret_cast<const v4u*>(seg + j);   // aligned 16B
        u32 n = hi - j;
        u32 rc0 = r4[0], rc1 = r4[1], rc2 = r4[2], rc3 = r4[3];
        u32 lid0 = rc0 & (NODES_PER_BIN - 1), sx0 = min(rc0 >> 11, (u32)(N_NODES - 1));
        u32 lid1 = rc1 & (NODES_PER_BIN - 1), sx1 = min(rc1 >> 11, (u32)(N_NODES - 1));
        u32 lid2 = rc2 & (NODES_PER_BIN - 1), sx2 = min(rc2 >> 11, (u32)(N_NODES - 1));
        u32 lid3 = rc3 & (NODES_PER_BIN - 1), sx3 = min(rc3 >> 11, (u32)(N_NODES - 1));

        // force 4 independent src-pos gathers into flight; one waitcnt for all.
        float2 ps0, ps1, ps2, ps3;
        asm volatile(
            "global_load_dwordx2 %0, %4, off\n\t"
            "global_load_dwordx2 %1, %5, off\n\t"
            "global_load_dwordx2 %2, %6, off\n\t"
            "global_load_dwordx2 %3, %7, off\n\t"
            "s_waitcnt vmcnt(0)"
            : "=&v"(ps0), "=&v"(ps1), "=&v"(ps2), "=&v"(ps3)
            : "v"(pos2 + sx0), "v"(pos2 + sx1), "v"(pos2 + sx2), "v"(pos2 + sx3));

        // dst-pos from the LDS window (no TA traffic)
        float2 pd0 = pwin[lid0];
        float2 pd1 = pwin[lid1];
        float2 pd2 = pwin[lid2];
        float2 pd3 = pwin[lid3];

        {
            float dx = ps0.x - pd0.x, dy = ps0.y - pd0.y;
            float nrm = sqrtf(dx * dx + dy * dy) + EPS;
            float inv = 1.0f / nrm;
            float ux = dx * inv, uy = dy * inv;
            float cdx = fminf(fmaxf(dx, -12.0f), 12.0f);
            float cdy = fminf(fmaxf(dy, -12.0f), 12.0f);
            u64 w = (u64)(u32)__float2int_rn((cdx + 12.0f) * 16.0f)
                  | ((u64)(u32)__float2int_rn((cdy + 12.0f) * 16.0f) << 16)
                  | ((u64)(u32)__float2int_rn((ux + 1.0f) * 16.0f) << 32)
                  | ((u64)(u32)__float2int_rn((uy + 1.0f) * 16.0f) << 44)
                  | (1ULL << 56);
            atomicAdd(&acc[lid0], w);
        }
        if (n > 1) {
            float dx = ps1.x - pd1.x, dy = ps1.y - pd1.y;
            float nrm = sqrtf(dx * dx + dy * dy) + EPS;
            float inv = 1.0f / nrm;
            float ux = dx * inv, uy = dy * inv;
            float cdx = fminf(fmaxf(dx, -12.0f), 12.0f);
            float cdy = fminf(fmaxf(dy, -12.0f), 12.0f);
            u64 w = (u64)(u32)__float2int_rn((cdx + 12.0f) * 16.0f)
                  | ((u64)(u32)__float2int_rn((cdy + 12.0f) * 16.0f) << 16)
                  | ((u64)(u32)__float2int_rn((ux + 1.0f) * 16.0f) << 32)
                  | ((u64)(u32)__float2int_rn((uy + 1.0f) * 16.0f) << 44)
                  | (1ULL << 56);
            atomicAdd(&acc[lid1], w);
        }
        if (n > 2) {
            float dx = ps2.x - pd2.x, dy = ps2.y - pd2.y;
            float nrm = sqrtf(dx * dx + dy * dy) + EPS;
            float inv = 1.0f / nrm;
            float ux = dx * inv, uy = dy * inv;
            float cdx = fminf(fmaxf(dx, -12.0f), 12.0f);
            float cdy = fminf(fmaxf(dy, -12.0f), 12.0f);
            u64 w = (u64)(u32)__float2int_rn((cdx + 12.0f) * 16.0f)
                  | ((u64)(u32)__float2int_rn((cdy + 12.0f) * 16.0f) << 16)
                  | ((u64)(u32)__float2int_rn((ux + 1.0f) * 16.0f) << 32)
                  | ((u64)(u32)__float2int_rn((uy + 1.0f) * 16.0f) << 44)
                  | (1ULL << 56);
            atomicAdd(&acc[lid2], w);
        }
        if (n > 3) {
            float dx = ps3.x - pd3.x, dy = ps3.y - pd3.y;
            float nrm = sqrtf(dx * dx + dy * dy) + EPS;
            float inv = 1.0f / nrm;
            float ux = dx * inv, uy = dy * inv;
            float cdx = fminf(fmaxf(dx, -12.0f), 12.0f);
            float cdy = fminf(fmaxf(dy, -12.0f), 12.0f);
            u64 w = (u64)(u32)__float2int_rn((cdx + 12.0f) * 16.0f)
                  | ((u64)(u32)__float2int_rn((cdy + 12.0f) * 16.0f) << 16)
                  | ((u64)(u32)__float2int_rn((ux + 1.0f) * 16.0f) << 32)
                  | ((u64)(u32)__float2int_rn((uy + 1.0f) * 16.0f) << 44)
                  | (1ULL << 56);
            atomicAdd(&acc[lid3], w);
        }
    }
    __syncthreads();

    u64* dstp = partial + ((size_t)k * SPLIT + s) * NODES_PER_BIN;
    #pragma unroll
    for (int i = 0; i < 4; ++i) {
        int idx = t + i * 512;
        __builtin_nontemporal_store(acc[idx], dstp + idx);
    }
}

// ---- Phase C: combine partials + finalize ----
__global__ void __launch_bounds__(512) combine_kernel(
    const u64* __restrict__ partial, const float* __restrict__ pos,
    float* __restrict__ out)
{
    int i = blockIdx.x * 512 + threadIdx.x;
    if (i >= N_NODES) return;
    int k = i >> 11;
    int lid = i & (NODES_PER_BIN - 1);
    const u64* p = partial + (size_t)k * SPLIT * NODES_PER_BIN + lid;
    u64 w = 0;
    #pragma unroll
    for (int s = 0; s < SPLIT; ++s)
        w += __builtin_nontemporal_load(p + (size_t)s * NODES_PER_BIN);

    float cnt = (float)(u32)(w >> 56);
    float sdx = (float)(u32)(w & 0xFFFFULL)         * (1.0f/16.0f) - 12.0f * cnt;
    float sdy = (float)(u32)((w >> 16) & 0xFFFFULL) * (1.0f/16.0f) - 12.0f * cnt;
    float sux = (float)(u32)((w >> 32) & 0xFFFULL)  * (1.0f/16.0f) -  1.0f * cnt;
    float suy = (float)(u32)((w >> 44) & 0xFFFULL)  * (1.0f/16.0f) -  1.0f * cnt;
    float invc = 1.0f / fmaxf(cnt, 1.0f);
    float2 pp = reinterpret_cast<const float2*>(pos)[i];
    float* row = out + (size_t)i * 6;
    row[0] = sdx * invc;
    row[1] = sdy * invc;
    row[2] = sux * invc;
    row[3] = suy * invc;
    row[4] = pp.x;
    row[5] = pp.y;
}

// ---------------- Fallback (round-3 single-atomic path) ----------------
__global__ void __launch_bounds__(256) edge_scatter_kernel(
    const int* __restrict__ src, const int* __restrict__ dst,
    const float* __restrict__ pos, u64* __restrict__ acc)
{
    int e = blockIdx.x * blockDim.x + threadIdx.x;
    if (e >= N_EDGES) return;
    int s = src[e];
    int d = dst[e];
    if ((unsigned)s >= (unsigned)N_NODES || (unsigned)d >= (unsigned)N_NODES) return;
    float2 ps = reinterpret_cast<const float2*>(pos)[s];
    float2 pd = reinterpret_cast<const float2*>(pos)[d];
    float dx = ps.x - pd.x, dy = ps.y - pd.y;
    float nrm = sqrtf(dx*dx + dy*dy) + EPS;
    float inv = 1.0f / nrm;
    float ux = dx * inv, uy = dy * inv;
    float cdx = fminf(fmaxf(dx, -12.0f), 12.0f);
    float cdy = fminf(fmaxf(dy, -12.0f), 12.0f);
    u64 qdx = (u64)(u32)__float2int_rn((cdx + 12.0f) * 16.0f);
    u64 qdy = (u64)(u32)__float2int_rn((cdy + 12.0f) * 16.0f);
    u64 qux = (u64)(u32)__float2int_rn((ux + 1.0f) * 16.0f);
    u64 quy = (u64)(u32)__float2int_rn((uy + 1.0f) * 16.0f);
    u64 w = qdx | (qdy << 16) | (qux << 32) | (quy << 44) | (1ULL << 56);
    atomicAdd(acc + (size_t)d * 3, w);
}

__global__ void __launch_bounds__(256) node_finalize_kernel(
    const float* __restrict__ pos, float* __restrict__ out)
{
    int i = blockIdx.x * blockDim.x + threadIdx.x;
    if (i >= N_NODES) return;
    u64 w = reinterpret_cast<const u64*>(out)[(size_t)i * 3];
    float cnt = (float)(u32)(w >> 56);
    float sdx = (float)(u32)(w & 0xFFFFULL)         * (1.0f/16.0f) - 12.0f * cnt;
    float sdy = (float)(u32)((w >> 16) & 0xFFFFULL) * (1.0f/16.0f) - 12.0f * cnt;
    float sux = (float)(u32)((w >> 32) & 0xFFFULL)  * (1.0f/16.0f) -  1.0f * cnt;
    float suy = (float)(u32)((w >> 44) & 0xFFFULL)  * (1.0f/16.0f) -  1.0f * cnt;
    float invc = 1.0f / fmaxf(cnt, 1.0f);
    float2 p = reinterpret_cast<const float2*>(pos)[i];
    float* row = out + (size_t)i * 6;
    row[0] = sdx * invc; row[1] = sdy * invc;
    row[2] = sux * invc; row[3] = suy * invc;
    row[4] = p.x; row[5] = p.y;
}

extern "C" void kernel_launch(void* const* d_in, const int* in_sizes, int n_in,
                              void* d_out, int out_size, void* d_ws, size_t ws_size,
                              hipStream_t stream)
{
    const float* pos = (const float*)d_in[0];
    const int* edge_index = (const int*)d_in[1];
    const int* src = edge_index;
    const int* dst = edge_index + N_EDGES;
    float* out = (float*)d_out;

    size_t need_rec    = ((size_t)N_EDGES + 4 * NBINS + 16) * sizeof(u32);      // ~64 MB
    size_t need_counts = (size_t)NBLK_A * NBINS * sizeof(u32);                  // ~2 MB
    size_t need_T      = (size_t)NBINS * sizeof(u32);
    size_t need_S      = (size_t)(NBINS + 1) * sizeof(u32);
    size_t need_Tlen   = (size_t)NBINS * sizeof(u32);
    size_t need_part   = (size_t)NBINS * SPLIT * NODES_PER_BIN * sizeof(u64);   // 32 MB
    size_t need = need_rec + need_counts + need_T + need_S + need_Tlen + need_part + 512;

    if (ws_size < need) {
        // Fallback: single-u64-atomic path (round 3)
        (void)hipMemsetAsync(d_out, 0, (size_t)out_size * sizeof(float), stream);
        int eblocks = (N_EDGES + 255) / 256;
        edge_scatter_kernel<<<eblocks, 256, 0, stream>>>(
            src, dst, pos, reinterpret_cast<u64*>(out));
        int nblocks = (N_NODES + 255) / 256;
        node_finalize_kernel<<<nblocks, 256, 0, stream>>>(pos, out);
        return;
    }

    char* w = (char*)d_ws;
    u32* recbuf  = (u32*)w;           w += need_rec;
    u32* counts  = (u32*)w;           w += need_counts;
    u32* T       = (u32*)w;           w += need_T;
    u32* S       = (u32*)w;           w += need_S;
    u32* Tlen    = (u32*)w;           w += need_Tlen;
    u64* partial = (u64*)w;

    hist_kernel   <<<NBLK_A, 512, 0, stream>>>(dst, counts);
    scanblk_kernel<<<NBINS,  256, 0, stream>>>(counts, T);
    scanbin_kernel<<<1,    NBINS, 0, stream>>>(T, S, Tlen);
    scatter_kernel<<<NBLK_A, 512, 0, stream>>>(src, dst, counts, S, recbuf);
    reduce_kernel <<<NBINS * SPLIT, 512, 0, stream>>>(recbuf, S, Tlen, pos, partial);
    combine_kernel<<<(N_NODES + 511) / 512, 512, 0, stream>>>(partial, pos, out);
}